// Round 1
// baseline (63.851 us; speedup 1.0000x reference)
//
#include <hip/hip_runtime.h>
#include <hip/hip_bf16.h>

typedef float  f32x4  __attribute__((ext_vector_type(4)));
typedef short  s16x8  __attribute__((ext_vector_type(8)));

__device__ __forceinline__ unsigned short f2bf(float f) {
    unsigned int u = __float_as_uint(f);
    unsigned int rnd = 0x7fffu + ((u >> 16) & 1u);   // round-to-nearest-even
    return (unsigned short)((u + rnd) >> 16);
}

// Kernel 1: build E[65536][128] (bf16) = combined embeddings.
//   rows [0,32768)      : q_emb   = (qe + sk + df + ar) / 4
//   rows [32768,65536)  : nq_emb  = (nqe + 5*(nsk+ndf+nar)) / 16   (double-avg quirk)
// Also converts Wq (f32 128x128) -> bf16 in first 16 blocks.
__global__ __launch_bounds__(256)
void h2kt_gather(const int* __restrict__ q, const int* __restrict__ next_q,
                 const float* __restrict__ ques_table,
                 const float* __restrict__ skill_table,
                 const float* __restrict__ diff_table,
                 const float* __restrict__ area_table,
                 const int* __restrict__ q2s,
                 const int* __restrict__ q2d,
                 const int* __restrict__ q2a,
                 const float* __restrict__ Wq,
                 unsigned short* __restrict__ E,
                 unsigned short* __restrict__ Wqb,
                 int pad_idx)
{
    if (blockIdx.x < 16) {
        int tid = blockIdx.x * 256 + threadIdx.x;       // 0..4095, 4 floats each
        float4 w4 = ((const float4*)Wq)[tid];
        ushort4 o;
        o.x = f2bf(w4.x); o.y = f2bf(w4.y); o.z = f2bf(w4.z); o.w = f2bf(w4.w);
        ((ushort4*)Wqb)[tid] = o;
    }

    const int wave = threadIdx.x >> 6;
    const int lane = threadIdx.x & 63;
    const int t = blockIdx.x * 4 + wave;                // 0..65535
    const int p = t & 32767;
    const bool isnq = (t >= 32768);

    const int qq = isnq ? next_q[p] : q[p];

    const float2 qe = *(const float2*)(ques_table + (size_t)qq * 128 + 2 * lane);

    const int* srow = q2s + (size_t)qq * 8;
    int sidx[8];
    #pragma unroll
    for (int i = 0; i < 8; ++i) sidx[i] = srow[i];

    float skx = 0.f, sky = 0.f; int cnt = 0;
    #pragma unroll
    for (int i = 0; i < 8; ++i) {
        if (sidx[i] != pad_idx) {                       // wave-uniform branch
            float2 sv = *(const float2*)(skill_table + (size_t)sidx[i] * 128 + 2 * lane);
            skx += sv.x; sky += sv.y; ++cnt;
        }
    }
    if (cnt > 0) { float inv = 1.f / (float)cnt; skx *= inv; sky *= inv; }

    const int di = q2d[qq];
    const int ai = q2a[qq];
    const float2 df = *(const float2*)(diff_table + (size_t)di * 128 + 2 * lane);
    const float2 ar = *(const float2*)(area_table + (size_t)ai * 128 + 2 * lane);

    float ex, ey;
    if (!isnq) {
        ex = 0.25f * (qe.x + skx + df.x + ar.x);
        ey = 0.25f * (qe.y + sky + df.y + ar.y);
    } else {
        ex = (qe.x + 5.f * (skx + df.x + ar.x)) * 0.0625f;
        ey = (qe.y + 5.f * (sky + df.y + ar.y)) * 0.0625f;
    }

    ushort2 st; st.x = f2bf(ex); st.y = f2bf(ey);
    ((ushort2*)(E + (size_t)t * 128))[lane] = st;
}

// Kernel 2: out = E @ Wq^T + bq, fused mask/concat epilogue.
// Wave handles 16 rows x 128 cols. mfma_f32_16x16x32_bf16:
//   A: lane holds A[row=lane&15][k=(lane>>4)*8 + i]  (8 contiguous bf16 -> 16B load)
//   B: lane holds B[k=(lane>>4)*8 + i][col=lane&15]  = Wq[col][k..k+7] row-major
//   D: lane holds D[row=(lane>>4)*4 + r][col=lane&15]
__global__ __launch_bounds__(256)
void h2kt_gemm(const unsigned short* __restrict__ E,
               const unsigned short* __restrict__ Wqb,
               const float* __restrict__ bq,
               const int* __restrict__ a_arr,
               float* __restrict__ out)
{
    const int wave = threadIdx.x >> 6;
    const int lane = threadIdx.x & 63;
    const int r0 = (blockIdx.x * 4 + wave) * 16;        // row-tile base, 0..65520
    const int cl = lane & 15;
    const int grp = lane >> 4;

    s16x8 afr[4];
    const s16x8* erow = (const s16x8*)(E + (size_t)(r0 + cl) * 128);
    #pragma unroll
    for (int kt = 0; kt < 4; ++kt) afr[kt] = erow[kt * 4 + grp];

    const bool isq = (r0 < 32768);
    int av[4];
    if (isq) {
        #pragma unroll
        for (int r = 0; r < 4; ++r) av[r] = a_arr[r0 + grp * 4 + r];
    }

    #pragma unroll
    for (int jt = 0; jt < 8; ++jt) {
        const s16x8* wrow = (const s16x8*)(Wqb + (size_t)(jt * 16 + cl) * 128);
        f32x4 acc = {0.f, 0.f, 0.f, 0.f};
        #pragma unroll
        for (int kt = 0; kt < 4; ++kt)
            acc = __builtin_amdgcn_mfma_f32_16x16x32_bf16(afr[kt], wrow[kt * 4 + grp], acc, 0, 0, 0);

        const float bqv = bq[jt * 16 + cl];
        #pragma unroll
        for (int r = 0; r < 4; ++r) {
            const int g = r0 + grp * 4 + r;
            const float v = acc[r] + bqv;
            if (isq) {
                const size_t base = (size_t)g * 384 + jt * 16 + cl;
                const bool on = (av[r] != 0);
                out[base]       = on ? v : 0.f;
                out[base + 128] = on ? 0.f : v;
            } else {
                out[(size_t)(g - 32768) * 384 + 256 + jt * 16 + cl] = v;
            }
        }
    }
}

extern "C" void kernel_launch(void* const* d_in, const int* in_sizes, int n_in,
                              void* d_out, int out_size, void* d_ws, size_t ws_size,
                              hipStream_t stream) {
    const int*   q          = (const int*)d_in[0];
    const int*   a          = (const int*)d_in[1];
    const int*   next_q     = (const int*)d_in[2];
    const float* ques_table = (const float*)d_in[3];
    const float* skill_tab  = (const float*)d_in[4];
    const float* diff_tab   = (const float*)d_in[5];
    const float* area_tab   = (const float*)d_in[6];
    const int*   q2s        = (const int*)d_in[7];
    const int*   q2d        = (const int*)d_in[8];
    const int*   q2a        = (const int*)d_in[9];
    const float* Wq         = (const float*)d_in[10];
    const float* bq         = (const float*)d_in[11];
    float* out = (float*)d_out;

    const int NS = in_sizes[4] / 128;       // 2001
    const int pad_idx = NS - 1;             // 2000

    unsigned short* E   = (unsigned short*)d_ws;            // 65536*128 bf16 = 16 MiB
    unsigned short* Wqb = E + (size_t)65536 * 128;          // 128*128 bf16

    h2kt_gather<<<16384, 256, 0, stream>>>(q, next_q, ques_table, skill_tab,
                                           diff_tab, area_tab, q2s, q2d, q2a,
                                           Wq, E, Wqb, pad_idx);
    h2kt_gemm<<<1024, 256, 0, stream>>>(E, Wqb, bq, a, out);
}